// Round 12
// baseline (61.259 us; speedup 1.0000x reference)
//
#include <hip/hip_runtime.h>
#include <math.h>

#define NEG_EPS 0.01f
#define LOG2E 1.4426950408889634f
#define LN2   0.6931471805599453f
#define NWS 390   // staged weight dwords in d_ws

typedef float f32x2  __attribute__((ext_vector_type(2)));
typedef float f32x4  __attribute__((ext_vector_type(4)));
typedef float f32x8  __attribute__((ext_vector_type(8)));
typedef float f32x16 __attribute__((ext_vector_type(16)));

#if __has_builtin(__builtin_amdgcn_exp2f)
#define EXP2F(x) __builtin_amdgcn_exp2f(x)
#else
#define EXP2F(x) exp2f(x)
#endif

struct Params {
  const float* W_in;  const float* b_in;
  const float* W_out; const float* b_out;
  const float* Wl_out;const float* bl_out;
  const float* Wp[4]; const float* bp[4];
  const float* Wl[4]; const float* bl[4];
};

// m = -Wr (positive); Wr is the NegativeLinear reparameterized weight
__device__ __forceinline__ float neg_rep_m(float v) {
  return (v >= 0.0f) ? expf(-v - NEG_EPS) : (expf(-NEG_EPS) - v);
}

// --- staged layout in d_ws (dwords), log2e folded into Wl/W_in/bias ---
__device__ float fetch_staged(int i, const Params& p) {
  if (i < 42) {
    int j = i / 6, c = i % 6;
    if (c < 3)  return LOG2E * p.W_in[j * 3 + c];
    if (c == 3) return 0.0f;
    return LOG2E * p.b_in[j];
  }
  i -= 42;
  if (i < 336) {
    int L = i / 84, r = i % 84, j = r / 12, c = r % 12;
    if (c < 7)  return neg_rep_m(p.Wp[L][j * 7 + c]);
    if (c < 10) return LOG2E * p.Wl[L][j * 3 + (c - 7)];
    return LOG2E * (p.bp[L][j] + p.bl[L][j]);
  }
  i -= 336;
  if (i < 7)  return neg_rep_m(p.W_out[i]);
  if (i < 10) return LOG2E * p.Wl_out[i - 7];
  return LOG2E * (p.b_out[0] + p.bl_out[0]);
}

__global__ void prep_weights(Params p, float* ws) {
  int i = threadIdx.x;
  if (i < NWS) ws[i] = fetch_staged(i, p);
}

// --- packed fp32 FMA broadcasts, R4-proven asm (SGPR half x both lanes) ---
__device__ __forceinline__ f32x2 pk_fma_lo(f32x2 w, f32x2 v, f32x2 c) {
  f32x2 d;
  asm("v_pk_fma_f32 %0, %1, %2, %3 op_sel:[0,0,0] op_sel_hi:[0,1,1]"
      : "=v"(d) : "s"(w), "v"(v), "v"(c));
  return d;
}
__device__ __forceinline__ f32x2 pk_fma_hi(f32x2 w, f32x2 v, f32x2 c) {
  f32x2 d;
  asm("v_pk_fma_f32 %0, %1, %2, %3 op_sel:[1,0,0] op_sel_hi:[1,1,1]"
      : "=v"(d) : "s"(w), "v"(v), "v"(c));
  return d;
}

// H(t) = max(t,0) + log2(1 + 2^-|t|), the log replaced by a deg-4 poly in
// u = 2e-1 (truncated shifted-Chebyshev of ln(3+u), rho=3-2sqrt2;
// max err ~1.0e-4, verified at u=-1,0,+1). PURE SCALAR fmaf: constants are
// hoisted to SGPRs once by the compiler (legal single-SGPR VOP3 operand).
__device__ __forceinline__ float H1f(float t) {
  float e = EXP2F(-fabsf(t));                       // trans pipe
  float u = fmaf(2.0f, e, -1.0f);
  float p = fmaf(-0.00500089f, u, 0.01943161f);
  p = fmaf(p, u, -0.07993738f);
  p = fmaf(p, u, 0.48048109f);
  return fmaf(p, u, fmaxf(t, 0.0f) + 0.58495149f);  // +E0 folded into max-term
}
__device__ __forceinline__ f32x2 H2f(f32x2 t) {
  f32x2 r;
  r.x = H1f(t.x);
  r.y = H1f(t.y);
  return r;
}

__device__ __forceinline__ f32x2 dot10(f32x2 w0, f32x2 w1, f32x2 w2_,
                                       f32x2 w3, f32x2 w4_, f32x2 w5,
                                       const f32x2 (&H)[7], const f32x2 (&X)[3]) {
  f32x2 acc = w5;                    // {bb,bb}
  acc = pk_fma_lo(w0, H[0], acc);
  acc = pk_fma_hi(w0, H[1], acc);
  acc = pk_fma_lo(w1, H[2], acc);
  acc = pk_fma_hi(w1, H[3], acc);
  acc = pk_fma_lo(w2_, H[4], acc);
  acc = pk_fma_hi(w2_, H[5], acc);
  acc = pk_fma_lo(w3, H[6], acc);
  acc = pk_fma_hi(w3, X[0], acc);
  acc = pk_fma_lo(w4_, X[1], acc);
  acc = pk_fma_hi(w4_, X[2], acc);
  return acc;
}

// pair extraction from SGPR tuples (compile-time p after unroll)
__device__ __forceinline__ f32x2 pair_in(const f32x16& a, const f32x16& b,
                                         const f32x8& c, const f32x2& d, int p) {
  if (p < 8)  return (f32x2){a[2 * p], a[2 * p + 1]};
  if (p < 16) { int q = 2 * (p - 8); return (f32x2){b[q], b[q + 1]}; }
  if (p < 20) { int q = 2 * (p - 16); return (f32x2){c[q], c[q + 1]}; }
  return d;
}
__device__ __forceinline__ f32x2 hpair(const f32x16& a0, const f32x16& a1,
                                       const f32x16& a2, const f32x16& a3,
                                       const f32x16& a4, const f32x4& a5, int p) {
  if (p < 8)  return (f32x2){a0[2 * p], a0[2 * p + 1]};
  if (p < 16) { int q = 2 * (p - 8);  return (f32x2){a1[q], a1[q + 1]}; }
  if (p < 24) { int q = 2 * (p - 16); return (f32x2){a2[q], a2[q + 1]}; }
  if (p < 32) { int q = 2 * (p - 24); return (f32x2){a3[q], a3[q + 1]}; }
  if (p < 40) { int q = 2 * (p - 32); return (f32x2){a4[q], a4[q + 1]}; }
  { int q = 2 * (p - 40); return (f32x2){a5[q], a5[q + 1]}; }
}

// one hidden layer: dst = H2f(Wp^r·src + Wl·x + b), 4 pair-streams
__device__ __forceinline__ void hidden_layer(const float* lp,
                                             const f32x2 (&S)[4][7],
                                             f32x2 (&Dst)[4][7],
                                             const f32x2 (&X)[4][3]) {
  f32x16 a0, a1, a2, a3, a4; f32x4 a5;
  asm volatile(
      "s_load_dwordx16 %0, %6, 0x0\n\t"
      "s_load_dwordx16 %1, %6, 0x40\n\t"
      "s_load_dwordx16 %2, %6, 0x80\n\t"
      "s_load_dwordx16 %3, %6, 0xc0\n\t"
      "s_load_dwordx16 %4, %6, 0x100\n\t"
      "s_load_dwordx4  %5, %6, 0x140\n\t"
      "s_waitcnt lgkmcnt(0)"
      : "=&s"(a0), "=&s"(a1), "=&s"(a2), "=&s"(a3), "=&s"(a4), "=&s"(a5)
      : "s"(lp));
  #pragma unroll
  for (int j = 0; j < 7; ++j) {
    const int P = 6 * j;
    f32x2 w0  = hpair(a0, a1, a2, a3, a4, a5, P + 0);
    f32x2 w1  = hpair(a0, a1, a2, a3, a4, a5, P + 1);
    f32x2 w2_ = hpair(a0, a1, a2, a3, a4, a5, P + 2);
    f32x2 w3  = hpair(a0, a1, a2, a3, a4, a5, P + 3);
    f32x2 w4_ = hpair(a0, a1, a2, a3, a4, a5, P + 4);
    f32x2 w5  = hpair(a0, a1, a2, a3, a4, a5, P + 5);
    #pragma unroll
    for (int s = 0; s < 4; ++s)
      Dst[s][j] = H2f(dot10(w0, w1, w2_, w3, w4_, w5, S[s], X[s]));
  }
}

// 8 rows per thread = 4 independent pair-streams
__global__ __launch_bounds__(256) void entropy_fwd(
    const float4* __restrict__ x4, float4* __restrict__ out4,
    const float* __restrict__ ws, int nthreads) {
  int idx = blockIdx.x * 256 + threadIdx.x;
  if (idx >= nthreads) return;

  float4 v0 = x4[idx * 6 + 0];
  float4 v1 = x4[idx * 6 + 1];
  float4 v2 = x4[idx * 6 + 2];
  float4 v3 = x4[idx * 6 + 3];
  float4 v4 = x4[idx * 6 + 4];
  float4 v5 = x4[idx * 6 + 5];

  f32x2 X[4][3];
  X[0][0] = {v0.x, v0.w}; X[0][1] = {v0.y, v1.x}; X[0][2] = {v0.z, v1.y};  // rows 0,1
  X[1][0] = {v1.z, v2.y}; X[1][1] = {v1.w, v2.z}; X[1][2] = {v2.x, v2.w};  // rows 2,3
  X[2][0] = {v3.x, v3.w}; X[2][1] = {v3.y, v4.x}; X[2][2] = {v3.z, v4.y};  // rows 4,5
  X[3][0] = {v4.z, v5.y}; X[3][1] = {v4.w, v5.z}; X[3][2] = {v5.x, v5.w};  // rows 6,7

  f32x2 H[4][7], N[4][7];

  // ---- input layer: 42 dwords -> SGPRs
  {
    f32x16 t0, t1; f32x8 t2; f32x2 t3;
    asm volatile(
        "s_load_dwordx16 %0, %4, 0x0\n\t"
        "s_load_dwordx16 %1, %4, 0x40\n\t"
        "s_load_dwordx8  %2, %4, 0x80\n\t"
        "s_load_dwordx2  %3, %4, 0xa0\n\t"
        "s_waitcnt lgkmcnt(0)"
        : "=&s"(t0), "=&s"(t1), "=&s"(t2), "=&s"(t3)
        : "s"(ws));
    #pragma unroll
    for (int j = 0; j < 7; ++j) {
      f32x2 p0 = pair_in(t0, t1, t2, t3, 3 * j + 0);
      f32x2 p1 = pair_in(t0, t1, t2, t3, 3 * j + 1);
      f32x2 p2 = pair_in(t0, t1, t2, t3, 3 * j + 2);
      #pragma unroll
      for (int s = 0; s < 4; ++s) {
        f32x2 t = p2;
        t = pk_fma_lo(p0, X[s][0], t);
        t = pk_fma_hi(p0, X[s][1], t);
        t = pk_fma_lo(p1, X[s][2], t);
        H[s][j] = H2f(t);
      }
    }
  }

  // ---- 4 hidden layers, ping-pong (even count -> result back in H)
  hidden_layer(ws + 42,  H, N, X);
  hidden_layer(ws + 126, N, H, X);
  hidden_layer(ws + 210, H, N, X);
  hidden_layer(ws + 294, N, H, X);

  // ---- output layer
  {
    f32x8 o0; f32x4 o1;
    asm volatile(
        "s_load_dwordx8 %0, %2, 0x0\n\t"
        "s_load_dwordx4 %1, %2, 0x20\n\t"
        "s_waitcnt lgkmcnt(0)"
        : "=&s"(o0), "=&s"(o1)
        : "s"(ws + 378));
    f32x2 w0  = {o0[0], o0[1]}, w1 = {o0[2], o0[3]};
    f32x2 w2_ = {o0[4], o0[5]}, w3 = {o0[6], o0[7]};
    f32x2 w4_ = {o1[0], o1[1]}, w5 = {o1[2], o1[3]};
    f32x2 R[4];
    #pragma unroll
    for (int s = 0; s < 4; ++s)
      R[s] = H2f(dot10(w0, w1, w2_, w3, w4_, w5, H[s], X[s]));
    float4 oa, ob;
    oa.x = -LN2 * R[0].x;  oa.y = -LN2 * R[0].y;
    oa.z = -LN2 * R[1].x;  oa.w = -LN2 * R[1].y;
    ob.x = -LN2 * R[2].x;  ob.y = -LN2 * R[2].y;
    ob.z = -LN2 * R[3].x;  ob.w = -LN2 * R[3].y;
    out4[idx * 2 + 0] = oa;
    out4[idx * 2 + 1] = ob;
  }
}

extern "C" void kernel_launch(void* const* d_in, const int* in_sizes, int n_in,
                              void* d_out, int out_size, void* d_ws, size_t ws_size,
                              hipStream_t stream) {
  (void)n_in; (void)ws_size;
  Params p;
  p.W_in   = (const float*)d_in[1];
  p.b_in   = (const float*)d_in[2];
  p.W_out  = (const float*)d_in[3];
  p.b_out  = (const float*)d_in[4];
  p.Wl_out = (const float*)d_in[5];
  p.bl_out = (const float*)d_in[6];
  for (int i = 0; i < 4; ++i) {
    p.Wp[i] = (const float*)d_in[7 + 4 * i];
    p.bp[i] = (const float*)d_in[8 + 4 * i];
    p.Wl[i] = (const float*)d_in[9 + 4 * i];
    p.bl[i] = (const float*)d_in[10 + 4 * i];
  }

  float* ws = (float*)d_ws;
  prep_weights<<<1, 512, 0, stream>>>(p, ws);

  int n_rows   = in_sizes[0] / 3;            // 4194304
  int nthreads = (n_rows + 7) / 8;           // 524288 (8 rows/thread)
  int blocks   = (nthreads + 255) / 256;     // 2048 blocks
  entropy_fwd<<<blocks, 256, 0, stream>>>(
      (const float4*)d_in[0], (float4*)d_out, ws, nthreads);
}

// Round 13
// 59.981 us; speedup vs baseline: 1.0213x; 1.0213x over previous
//
#include <hip/hip_runtime.h>
#include <math.h>

#define NEG_EPS 0.01f
#define LOG2E 1.4426950408889634f
#define LN2   0.6931471805599453f
#define NWS 390   // staged weight dwords in d_ws

typedef float f32x2  __attribute__((ext_vector_type(2)));

#if __has_builtin(__builtin_amdgcn_exp2f)
#define EXP2F(x) __builtin_amdgcn_exp2f(x)
#else
#define EXP2F(x) exp2f(x)
#endif
#if __has_builtin(__builtin_amdgcn_logf)
#define LOG2F(x) __builtin_amdgcn_logf(x)
#else
#define LOG2F(x) __log2f(x)
#endif

struct Params {
  const float* W_in;  const float* b_in;
  const float* W_out; const float* b_out;
  const float* Wl_out;const float* bl_out;
  const float* Wp[4]; const float* bp[4];
  const float* Wl[4]; const float* bl[4];
};

// m = -Wr (positive); Wr is the NegativeLinear reparameterized weight
__device__ __forceinline__ float neg_rep_m(float v) {
  return (v >= 0.0f) ? expf(-v - NEG_EPS) : (expf(-NEG_EPS) - v);
}

// --- staged layout in d_ws (dwords), log2e folded into Wl/W_in/bias ---
//  pairs 0..20   : input neuron j at pair 3j: {cW0,cW1}{cW2,0}{cb,cb}
//  pairs 21+42L  : hidden L neuron j at 6j: {m0,m1}{m2,m3}{m4,m5}{m6,cwl0}{cwl1,cwl2}{cbb,cbb}
//  pairs 189..194: output, same 6-pair record
__device__ float fetch_staged(int i, const Params& p) {
  if (i < 42) {
    int j = i / 6, c = i % 6;
    if (c < 3)  return LOG2E * p.W_in[j * 3 + c];
    if (c == 3) return 0.0f;
    return LOG2E * p.b_in[j];
  }
  i -= 42;
  if (i < 336) {
    int L = i / 84, r = i % 84, j = r / 12, c = r % 12;
    if (c < 7)  return neg_rep_m(p.Wp[L][j * 7 + c]);
    if (c < 10) return LOG2E * p.Wl[L][j * 3 + (c - 7)];
    return LOG2E * (p.bp[L][j] + p.bl[L][j]);
  }
  i -= 336;
  if (i < 7)  return neg_rep_m(p.W_out[i]);
  if (i < 10) return LOG2E * p.Wl_out[i - 7];
  return LOG2E * (p.b_out[0] + p.bl_out[0]);
}

__global__ void prep_weights(Params p, float* ws) {
  int i = threadIdx.x;
  if (i < NWS) ws[i] = fetch_staged(i, p);
}

// --- packed fp32 FMA broadcasts, R4-proven asm (SGPR half x both lanes) ---
__device__ __forceinline__ f32x2 pk_fma_lo(f32x2 w, f32x2 v, f32x2 c) {
  f32x2 d;
  asm("v_pk_fma_f32 %0, %1, %2, %3 op_sel:[0,0,0] op_sel_hi:[0,1,1]"
      : "=v"(d) : "s"(w), "v"(v), "v"(c));
  return d;
}
__device__ __forceinline__ f32x2 pk_fma_hi(f32x2 w, f32x2 v, f32x2 c) {
  f32x2 d;
  asm("v_pk_fma_f32 %0, %1, %2, %3 op_sel:[1,0,0] op_sel_hi:[1,1,1]"
      : "=v"(d) : "s"(w), "v"(v), "v"(c));
  return d;
}

// H(t) = max(t,0) + log2(1 + 2^-|t|) — R9/R11-proven: exp/log on trans pipe,
// packed add/max around them.
__device__ __forceinline__ f32x2 H2f(f32x2 t) {
  const f32x2 ONE  = {1.0f, 1.0f};
  const f32x2 ZERO = {0.0f, 0.0f};
  f32x2 e;
  e.x = EXP2F(-fabsf(t.x));
  e.y = EXP2F(-fabsf(t.y));
  f32x2 a = e + ONE;                    // v_pk_add_f32
  f32x2 l;
  l.x = LOG2F(a.x);
  l.y = LOG2F(a.y);
#if __has_builtin(__builtin_elementwise_max)
  f32x2 mx = __builtin_elementwise_max(t, ZERO);   // v_pk_max_f32
#else
  f32x2 mx; mx.x = fmaxf(t.x, 0.0f); mx.y = fmaxf(t.y, 0.0f);
#endif
  return mx + l;                        // v_pk_add_f32
}

__device__ __forceinline__ f32x2 dot10(f32x2 w0, f32x2 w1, f32x2 w2_,
                                       f32x2 w3, f32x2 w4_, f32x2 w5,
                                       const f32x2 (&H)[7], const f32x2 (&X)[3]) {
  f32x2 acc = w5;                    // {bb,bb}
  acc = pk_fma_lo(w0, H[0], acc);
  acc = pk_fma_hi(w0, H[1], acc);
  acc = pk_fma_lo(w1, H[2], acc);
  acc = pk_fma_hi(w1, H[3], acc);
  acc = pk_fma_lo(w2_, H[4], acc);
  acc = pk_fma_hi(w2_, H[5], acc);
  acc = pk_fma_lo(w3, H[6], acc);
  acc = pk_fma_hi(w3, X[0], acc);
  acc = pk_fma_lo(w4_, X[1], acc);
  acc = pk_fma_hi(w4_, X[2], acc);
  return acc;
}

// one hidden layer: dst = H2f(Wp^r·src + Wl·x + b), 4 pair-streams.
// Weights via PLAIN uniform loads -> compiler emits mergeable s_loads it can
// hoist/prefetch across layers (no volatile-asm scheduling barriers).
__device__ __forceinline__ void hidden_layer(const f32x2* __restrict__ base,
                                             const f32x2 (&S)[4][7],
                                             f32x2 (&Dst)[4][7],
                                             const f32x2 (&X)[4][3]) {
  #pragma unroll
  for (int j = 0; j < 7; ++j) {
    f32x2 w0  = base[6 * j + 0];
    f32x2 w1  = base[6 * j + 1];
    f32x2 w2_ = base[6 * j + 2];
    f32x2 w3  = base[6 * j + 3];
    f32x2 w4_ = base[6 * j + 4];
    f32x2 w5  = base[6 * j + 5];
    #pragma unroll
    for (int s = 0; s < 4; ++s)
      Dst[s][j] = H2f(dot10(w0, w1, w2_, w3, w4_, w5, S[s], X[s]));
  }
}

// 8 rows per thread = 4 independent pair-streams
__global__ __launch_bounds__(256) void entropy_fwd(
    const float4* __restrict__ x4, float4* __restrict__ out4,
    const float* __restrict__ ws, int nthreads) {
  int idx = blockIdx.x * 256 + threadIdx.x;
  if (idx >= nthreads) return;

  const f32x2* __restrict__ w2 = (const f32x2*)ws;

  float4 v0 = x4[idx * 6 + 0];
  float4 v1 = x4[idx * 6 + 1];
  float4 v2 = x4[idx * 6 + 2];
  float4 v3 = x4[idx * 6 + 3];
  float4 v4 = x4[idx * 6 + 4];
  float4 v5 = x4[idx * 6 + 5];

  f32x2 X[4][3];
  X[0][0] = {v0.x, v0.w}; X[0][1] = {v0.y, v1.x}; X[0][2] = {v0.z, v1.y};  // rows 0,1
  X[1][0] = {v1.z, v2.y}; X[1][1] = {v1.w, v2.z}; X[1][2] = {v2.x, v2.w};  // rows 2,3
  X[2][0] = {v3.x, v3.w}; X[2][1] = {v3.y, v4.x}; X[2][2] = {v3.z, v4.y};  // rows 4,5
  X[3][0] = {v4.z, v5.y}; X[3][1] = {v4.w, v5.z}; X[3][2] = {v5.x, v5.w};  // rows 6,7

  f32x2 H[4][7], N[4][7];

  // ---- input layer
  #pragma unroll
  for (int j = 0; j < 7; ++j) {
    f32x2 p0 = w2[3 * j + 0];
    f32x2 p1 = w2[3 * j + 1];
    f32x2 p2 = w2[3 * j + 2];
    #pragma unroll
    for (int s = 0; s < 4; ++s) {
      f32x2 t = p2;
      t = pk_fma_lo(p0, X[s][0], t);
      t = pk_fma_hi(p0, X[s][1], t);
      t = pk_fma_lo(p1, X[s][2], t);
      H[s][j] = H2f(t);
    }
  }

  // ---- 4 hidden layers, ping-pong (even count -> result back in H)
  hidden_layer(w2 + 21 + 0 * 42, H, N, X);
  hidden_layer(w2 + 21 + 1 * 42, N, H, X);
  hidden_layer(w2 + 21 + 2 * 42, H, N, X);
  hidden_layer(w2 + 21 + 3 * 42, N, H, X);

  // ---- output layer
  {
    const f32x2* __restrict__ ob_ = w2 + 189;
    f32x2 w0  = ob_[0], w1 = ob_[1], w2_ = ob_[2];
    f32x2 w3  = ob_[3], w4_ = ob_[4], w5 = ob_[5];
    f32x2 R[4];
    #pragma unroll
    for (int s = 0; s < 4; ++s)
      R[s] = H2f(dot10(w0, w1, w2_, w3, w4_, w5, H[s], X[s]));
    float4 oa, obv;
    oa.x  = -LN2 * R[0].x;  oa.y  = -LN2 * R[0].y;
    oa.z  = -LN2 * R[1].x;  oa.w  = -LN2 * R[1].y;
    obv.x = -LN2 * R[2].x;  obv.y = -LN2 * R[2].y;
    obv.z = -LN2 * R[3].x;  obv.w = -LN2 * R[3].y;
    out4[idx * 2 + 0] = oa;
    out4[idx * 2 + 1] = obv;
  }
}

extern "C" void kernel_launch(void* const* d_in, const int* in_sizes, int n_in,
                              void* d_out, int out_size, void* d_ws, size_t ws_size,
                              hipStream_t stream) {
  (void)n_in; (void)ws_size;
  Params p;
  p.W_in   = (const float*)d_in[1];
  p.b_in   = (const float*)d_in[2];
  p.W_out  = (const float*)d_in[3];
  p.b_out  = (const float*)d_in[4];
  p.Wl_out = (const float*)d_in[5];
  p.bl_out = (const float*)d_in[6];
  for (int i = 0; i < 4; ++i) {
    p.Wp[i] = (const float*)d_in[7 + 4 * i];
    p.bp[i] = (const float*)d_in[8 + 4 * i];
    p.Wl[i] = (const float*)d_in[9 + 4 * i];
    p.bl[i] = (const float*)d_in[10 + 4 * i];
  }

  float* ws = (float*)d_ws;
  prep_weights<<<1, 512, 0, stream>>>(p, ws);

  int n_rows   = in_sizes[0] / 3;            // 4194304
  int nthreads = (n_rows + 7) / 8;           // 524288 (8 rows/thread)
  int blocks   = (nthreads + 255) / 256;     // 2048 blocks
  entropy_fwd<<<blocks, 256, 0, stream>>>(
      (const float4*)d_in[0], (float4*)d_out, ws, nthreads);
}